// Round 1
// baseline (1029.046 us; speedup 1.0000x reference)
//
#include <hip/hip_runtime.h>
#include <math.h>

#define T 512              // threads per block (8 waves)
#define R 8                // anchor rows per block
#define BB 4096            // batch size
#define DD 128             // feature dim
#define NQ (DD/4)          // 32 float4 quads per row

constexpr float POS_W  = 2.0f;
constexpr float NEG_W  = 40.0f;
constexpr float MARGIN = 0.1f;
constexpr float THRESH = 0.5f;
constexpr float INV_TAU = 0.25f;   // 1/4
constexpr float BETA   = 0.5f;

__device__ __forceinline__ float dot4(float4 a, float4 b) {
  return a.x*b.x + a.y*b.y + a.z*b.z + a.w*b.w;
}

template<int OPK>  // 0=sum 1=min 2=max
__device__ __forceinline__ float wred(float v) {
#pragma unroll
  for (int o = 32; o; o >>= 1) {
    float t = __shfl_xor(v, o);
    v = (OPK == 0) ? (v + t) : (OPK == 1 ? fminf(v, t) : fmaxf(v, t));
  }
  return v;
}

// block-wide reduce of arr[R] (per-thread partials) into shared OUTS[R]
#define REDUCE_R(arr, OPK, OUTS) do {                                        \
  _Pragma("unroll")                                                          \
  for (int r_ = 0; r_ < R; ++r_) {                                           \
    float v_ = wred<OPK>(arr[r_]);                                           \
    if (lane == 0) red[wid][r_] = v_;                                        \
  }                                                                          \
  __syncthreads();                                                           \
  if (tid < R) {                                                             \
    float x_ = red[0][tid];                                                  \
    _Pragma("unroll")                                                        \
    for (int w_ = 1; w_ < T/64; ++w_) {                                      \
      float t_ = red[w_][tid];                                               \
      x_ = (OPK == 0) ? (x_ + t_) : (OPK == 1 ? fminf(x_, t_) : fmaxf(x_, t_)); \
    }                                                                        \
    OUTS[tid] = x_;                                                          \
  }                                                                          \
  __syncthreads();                                                           \
} while (0)

__global__ __launch_bounds__(T, 2) void crit_main(
    const float* __restrict__ batch,
    const float* __restrict__ teacher,
    const int*   __restrict__ labels,
    double*      __restrict__ acc,      // [0]=rank_sum, [1]=kd_sum
    int*         __restrict__ nvalid)
{
  __shared__ float4 sA[R][NQ];
  __shared__ float4 sT[R][NQ];
  __shared__ int    sLab[R];
  __shared__ float  red[T/64][R];
  __shared__ float  sMP[R], sMN[R], sZS[R], sZT[R], sW[R], sPS[R], sNS[R];

  const int tid  = threadIdx.x;
  const int lane = tid & 63;
  const int wid  = tid >> 6;
  const int i0   = blockIdx.x * R;

  const float4* b4 = reinterpret_cast<const float4*>(batch);
  const float4* t4 = reinterpret_cast<const float4*>(teacher);

  for (int idx = tid; idx < R*NQ; idx += T) {
    int r = idx / NQ, q = idx % NQ;
    sA[r][q] = b4[(size_t)(i0 + r) * NQ + q];
    sT[r][q] = t4[(size_t)(i0 + r) * NQ + q];
  }
  if (tid < R) sLab[tid] = labels[i0 + tid];
  __syncthreads();

  int labR[R];
#pragma unroll
  for (int r = 0; r < R; ++r) labR[r] = sLab[r];

  float sims[8][R];    // retained sim values: [j-slot][anchor]
  int   jlab[8];
  float zs[R], zt[R], wv[R], mp[R], mn[R];
#pragma unroll
  for (int r = 0; r < R; ++r) {
    zs[r] = 0.f; zt[r] = 0.f; wv[r] = 0.f;
    mp[r] = INFINITY; mn[r] = -INFINITY;
  }

#pragma unroll
  for (int g = 0; g < 2; ++g) {          // two groups of 4 j's per thread
    float accS[4][R], accT[4][R];
#pragma unroll
    for (int u = 0; u < 4; ++u)
#pragma unroll
      for (int r = 0; r < R; ++r) { accS[u][r] = 0.f; accT[u][r] = 0.f; }

    const int jb = tid + T*4*g;
#pragma unroll
    for (int u = 0; u < 4; ++u) jlab[4*g + u] = labels[jb + T*u];

    const float4* br0 = b4 + (size_t)jb * NQ;
    const float4* tr0 = t4 + (size_t)jb * NQ;

#pragma unroll 1
    for (int kc = 0; kc < NQ/4; ++kc) {  // 8 chunks of 16 dims (one 64B line per row)
#pragma unroll
      for (int up = 0; up < 2; ++up) {
        const int u0 = 2*up, u1 = 2*up + 1;
        // ---- batch half: load both rows' full 64B line back-to-back (MSHR merge)
        float4 bq0[4], bq1[4];
#pragma unroll
        for (int q = 0; q < 4; ++q) bq0[q] = br0[(size_t)(T*u0)*NQ + kc*4 + q];
#pragma unroll
        for (int q = 0; q < 4; ++q) bq1[q] = br0[(size_t)(T*u1)*NQ + kc*4 + q];
#pragma unroll
        for (int q = 0; q < 4; ++q) {
#pragma unroll
          for (int r = 0; r < R; ++r) {
            float4 a = sA[r][kc*4 + q];          // broadcast LDS read
            accS[u0][r] += dot4(a, bq0[q]);
            accS[u1][r] += dot4(a, bq1[q]);
          }
        }
        // ---- teacher half
        float4 tq0[4], tq1[4];
#pragma unroll
        for (int q = 0; q < 4; ++q) tq0[q] = tr0[(size_t)(T*u0)*NQ + kc*4 + q];
#pragma unroll
        for (int q = 0; q < 4; ++q) tq1[q] = tr0[(size_t)(T*u1)*NQ + kc*4 + q];
#pragma unroll
        for (int q = 0; q < 4; ++q) {
#pragma unroll
          for (int r = 0; r < R; ++r) {
            float4 a = sT[r][kc*4 + q];
            accT[u0][r] += dot4(a, tq0[q]);
            accT[u1][r] += dot4(a, tq1[q]);
          }
        }
      }
    }

    // ---- epilogue for this group: streaming KD accumulation + min/max tracking
#pragma unroll
    for (int u = 0; u < 4; ++u) {
      const int j  = jb + T*u;
      const int lj = jlab[4*g + u];
#pragma unroll
      for (int r = 0; r < R; ++r) {
        float sim  = accS[u][r];
        float tsim = accT[u][r];
        bool same  = (lj == labR[r]);
        float scale = same ? 1.0f : BETA;
        float s  = sim  * scale * INV_TAU;
        float ts = tsim * scale * INV_TAU;
        float es = expf(s);
        float et = expf(ts);
        zs[r] += es;
        zt[r] += et;
        wv[r] += et * (ts - s);
        if (same) {
          if (j != i0 + r) mp[r] = fminf(mp[r], sim);
        } else {
          mn[r] = fmaxf(mn[r], sim);
        }
        sims[4*g + u][r] = sim;
      }
    }
  }

  // ---- block-wide reductions (full row per block => full-row stats)
  REDUCE_R(mp, 1, sMP);
  REDUCE_R(mn, 2, sMN);
  REDUCE_R(zs, 0, sZS);
  REDUCE_R(zt, 0, sZT);
  REDUCE_R(wv, 0, sW);

  // ---- pass 2: masked rank-loss sums from retained sims
  float ps[R], ns[R];
#pragma unroll
  for (int r = 0; r < R; ++r) { ps[r] = 0.f; ns[r] = 0.f; }
#pragma unroll
  for (int p = 0; p < 8; ++p) {
    const int j  = tid + T*p;
    const int lj = jlab[p];
#pragma unroll
    for (int r = 0; r < R; ++r) {
      float sim = sims[p][r];
      if (lj == labR[r]) {
        if (j != i0 + r && (sim - MARGIN < sMN[r]))
          ps[r] += expf(-POS_W * (sim - THRESH));
      } else {
        if (sim + MARGIN > sMP[r])
          ns[r] += expf(NEG_W * (sim - THRESH));
      }
    }
  }
  REDUCE_R(ps, 0, sPS);
  REDUCE_R(ns, 0, sNS);

  // ---- per-anchor finalize + global accumulation
  if (tid < R) {
    // KD: kl = W/Zt + log(Zs) - log(Zt)
    float kl = sW[tid] / sZT[tid] + logf(sZS[tid]) - logf(sZT[tid]);
    atomicAdd(&acc[1], (double)kl);

    float psum = sPS[tid], nsum = sNS[tid];
    // exp(..) > 0 always in fp32 here, so sum>0 <=> any kept
    if (psum > 0.f && nsum > 0.f) {
      float term = log1pf(psum) * (1.0f/POS_W) + log1pf(nsum) * (1.0f/NEG_W);
      atomicAdd(&acc[0], (double)term);
      atomicAdd(nvalid, 1);
    }
  }
}

__global__ void crit_final(const double* __restrict__ acc,
                           const int*    __restrict__ nvalid,
                           const int*    __restrict__ epoch,
                           float*        __restrict__ out)
{
  int nv = *nvalid;
  double loss_rank = acc[0] / (double)(nv < 1 ? 1 : nv);
  double loss_kd   = acc[1] / (double)BB;
  double wgt = ((double)(*epoch)) * 0.01 * 16.0;   // epoch/100 * ALPHA * TAU^2
  out[0] = (float)(loss_rank + wgt * loss_kd);
  out[1] = (float)loss_rank;
  out[2] = (float)loss_kd;
}

extern "C" void kernel_launch(void* const* d_in, const int* in_sizes, int n_in,
                              void* d_out, int out_size, void* d_ws, size_t ws_size,
                              hipStream_t stream)
{
  (void)in_sizes; (void)n_in; (void)out_size; (void)ws_size;
  const float* batch   = (const float*)d_in[0];
  const float* teacher = (const float*)d_in[1];
  const int*   labels  = (const int*)d_in[2];
  const int*   epoch   = (const int*)d_in[3];
  float* out  = (float*)d_out;
  double* acc = (double*)d_ws;
  int* nv     = (int*)((char*)d_ws + 16);

  hipMemsetAsync(d_ws, 0, 32, stream);
  crit_main<<<dim3(BB / R), dim3(T), 0, stream>>>(batch, teacher, labels, acc, nv);
  crit_final<<<dim3(1), dim3(1), 0, stream>>>(acc, nv, epoch, out);
}

// Round 2
// 380.754 us; speedup vs baseline: 2.7027x; 2.7027x over previous
//
#include <hip/hip_runtime.h>
#include <math.h>

#define T 512              // threads per block (8 waves)
#define R 8                // anchor rows per block
#define BB 4096            // batch size
#define DD 128             // feature dim
#define NQ (DD/4)          // 32 float4 quads per row

constexpr float POS_W  = 2.0f;
constexpr float NEG_W  = 40.0f;
constexpr float MARGIN = 0.1f;
constexpr float THRESH = 0.5f;
constexpr float INV_TAU = 0.25f;   // 1/4
constexpr float BETA   = 0.5f;

__device__ __forceinline__ float dot4(float4 a, float4 b) {
  return a.x*b.x + a.y*b.y + a.z*b.z + a.w*b.w;
}

template<int OPK>  // 0=sum 1=min 2=max
__device__ __forceinline__ float wred(float v) {
#pragma unroll
  for (int o = 32; o; o >>= 1) {
    float t = __shfl_xor(v, o);
    v = (OPK == 0) ? (v + t) : (OPK == 1 ? fminf(v, t) : fmaxf(v, t));
  }
  return v;
}

#define REDUCE_R(arr, OPK, OUTS) do {                                        \
  _Pragma("unroll")                                                          \
  for (int r_ = 0; r_ < R; ++r_) {                                           \
    float v_ = wred<OPK>(arr[r_]);                                           \
    if (lane == 0) red[wid][r_] = v_;                                        \
  }                                                                          \
  __syncthreads();                                                           \
  if (tid < R) {                                                             \
    float x_ = red[0][tid];                                                  \
    _Pragma("unroll")                                                        \
    for (int w_ = 1; w_ < T/64; ++w_) {                                      \
      float t_ = red[w_][tid];                                               \
      x_ = (OPK == 0) ? (x_ + t_) : (OPK == 1 ? fminf(x_, t_) : fmaxf(x_, t_)); \
    }                                                                        \
    OUTS[tid] = x_;                                                          \
  }                                                                          \
  __syncthreads();                                                           \
} while (0)

__global__ __launch_bounds__(T, 1) void crit_main(
    const float* __restrict__ batch,
    const float* __restrict__ teacher,
    const int*   __restrict__ labels,
    double*      __restrict__ acc,
    int*         __restrict__ nvalid)
{
  __shared__ float4 sA[R][NQ];
  __shared__ float4 sT[R][NQ];
  __shared__ int    sLab[R];
  __shared__ float  red[T/64][R];
  __shared__ float  sMP[R], sMN[R], sZS[R], sZT[R], sW[R], sPS[R], sNS[R];

  const int tid  = threadIdx.x;
  const int lane = tid & 63;
  const int wid  = tid >> 6;
  const int i0   = blockIdx.x * R;

  const float4* b4 = reinterpret_cast<const float4*>(batch);
  const float4* t4 = reinterpret_cast<const float4*>(teacher);

  for (int idx = tid; idx < R*NQ; idx += T) {
    int r = idx / NQ, q = idx % NQ;
    sA[r][q] = b4[(size_t)(i0 + r) * NQ + q];
    sT[r][q] = t4[(size_t)(i0 + r) * NQ + q];
  }
  if (tid < R) sLab[tid] = labels[i0 + tid];
  __syncthreads();

  int labR[R];
#pragma unroll
  for (int r = 0; r < R; ++r) labR[r] = sLab[r];

  float sims[8][R];    // raw batch sims: [j-slot][anchor]
  int   jlab[8];
  float zs[R], mp[R], mn[R];
#pragma unroll
  for (int r = 0; r < R; ++r) {
    zs[r] = 0.f; mp[r] = INFINITY; mn[r] = -INFINITY;
  }

  // =============== Phase A: batch sims ===============
#pragma unroll
  for (int g = 0; g < 2; ++g) {
    float accS[4][R];
#pragma unroll
    for (int u = 0; u < 4; ++u)
#pragma unroll
      for (int r = 0; r < R; ++r) accS[u][r] = 0.f;

    const int jb = tid + T*4*g;
#pragma unroll
    for (int u = 0; u < 4; ++u) jlab[4*g + u] = labels[jb + T*u];

    const float4* br0 = b4 + (size_t)jb * NQ;

#pragma unroll 1
    for (int kc = 0; kc < NQ/4; ++kc) {
#pragma unroll
      for (int up = 0; up < 2; ++up) {
        const int u0 = 2*up, u1 = 2*up + 1;
        float4 bq0[4], bq1[4];
#pragma unroll
        for (int q = 0; q < 4; ++q) bq0[q] = br0[(size_t)(T*u0)*NQ + kc*4 + q];
#pragma unroll
        for (int q = 0; q < 4; ++q) bq1[q] = br0[(size_t)(T*u1)*NQ + kc*4 + q];
#pragma unroll
        for (int q = 0; q < 4; ++q) {
#pragma unroll
          for (int r = 0; r < R; ++r) {
            float4 a = sA[r][kc*4 + q];
            accS[u0][r] += dot4(a, bq0[q]);
            accS[u1][r] += dot4(a, bq1[q]);
          }
        }
      }
    }

#pragma unroll
    for (int u = 0; u < 4; ++u) {
      const int j  = jb + T*u;
      const int lj = jlab[4*g + u];
#pragma unroll
      for (int r = 0; r < R; ++r) {
        float sim = accS[u][r];
        bool same = (lj == labR[r]);
        float s   = sim * (same ? 1.0f : BETA) * INV_TAU;
        zs[r] += __expf(s);
        if (same) {
          if (j != i0 + r) mp[r] = fminf(mp[r], sim);
        } else {
          mn[r] = fmaxf(mn[r], sim);
        }
        sims[4*g + u][r] = sim;
      }
    }
  }

  REDUCE_R(mp, 1, sMP);
  REDUCE_R(mn, 2, sMN);
  REDUCE_R(zs, 0, sZS);

  // =============== Phase B: teacher sims + KD ===============
  float zt[R], wv[R];
#pragma unroll
  for (int r = 0; r < R; ++r) { zt[r] = 0.f; wv[r] = 0.f; }

#pragma unroll
  for (int g = 0; g < 2; ++g) {
    float accT[4][R];
#pragma unroll
    for (int u = 0; u < 4; ++u)
#pragma unroll
      for (int r = 0; r < R; ++r) accT[u][r] = 0.f;

    const int jb = tid + T*4*g;
    const float4* tr0 = t4 + (size_t)jb * NQ;

#pragma unroll 1
    for (int kc = 0; kc < NQ/4; ++kc) {
#pragma unroll
      for (int up = 0; up < 2; ++up) {
        const int u0 = 2*up, u1 = 2*up + 1;
        float4 tq0[4], tq1[4];
#pragma unroll
        for (int q = 0; q < 4; ++q) tq0[q] = tr0[(size_t)(T*u0)*NQ + kc*4 + q];
#pragma unroll
        for (int q = 0; q < 4; ++q) tq1[q] = tr0[(size_t)(T*u1)*NQ + kc*4 + q];
#pragma unroll
        for (int q = 0; q < 4; ++q) {
#pragma unroll
          for (int r = 0; r < R; ++r) {
            float4 a = sT[r][kc*4 + q];
            accT[u0][r] += dot4(a, tq0[q]);
            accT[u1][r] += dot4(a, tq1[q]);
          }
        }
      }
    }

#pragma unroll
    for (int u = 0; u < 4; ++u) {
      const int lj = jlab[4*g + u];
#pragma unroll
      for (int r = 0; r < R; ++r) {
        float tsim = accT[u][r];
        bool same  = (lj == labR[r]);
        float scale = (same ? 1.0f : BETA) * INV_TAU;
        float s  = sims[4*g + u][r] * scale;
        float ts = tsim * scale;
        float et = __expf(ts);
        zt[r] += et;
        wv[r] += et * (ts - s);
      }
    }
  }

  REDUCE_R(zt, 0, sZT);
  REDUCE_R(wv, 0, sW);

  // =============== pass 2: masked rank sums ===============
  float ps[R], ns[R];
#pragma unroll
  for (int r = 0; r < R; ++r) { ps[r] = 0.f; ns[r] = 0.f; }
#pragma unroll
  for (int p = 0; p < 8; ++p) {
    const int j  = tid + T*p;
    const int lj = jlab[p];
#pragma unroll
    for (int r = 0; r < R; ++r) {
      float sim = sims[p][r];
      if (lj == labR[r]) {
        if (j != i0 + r && (sim - MARGIN < sMN[r]))
          ps[r] += __expf(-POS_W * (sim - THRESH));
      } else {
        if (sim + MARGIN > sMP[r])
          ns[r] += __expf(NEG_W * (sim - THRESH));
      }
    }
  }
  REDUCE_R(ps, 0, sPS);
  REDUCE_R(ns, 0, sNS);

  if (tid < R) {
    float kl = sW[tid] / sZT[tid] + __logf(sZS[tid]) - __logf(sZT[tid]);
    atomicAdd(&acc[1], (double)kl);

    float psum = sPS[tid], nsum = sNS[tid];
    if (psum > 0.f && nsum > 0.f) {
      float term = log1pf(psum) * (1.0f/POS_W) + log1pf(nsum) * (1.0f/NEG_W);
      atomicAdd(&acc[0], (double)term);
      atomicAdd(nvalid, 1);
    }
  }
}

__global__ void crit_final(const double* __restrict__ acc,
                           const int*    __restrict__ nvalid,
                           const int*    __restrict__ epoch,
                           float*        __restrict__ out)
{
  int nv = *nvalid;
  double loss_rank = acc[0] / (double)(nv < 1 ? 1 : nv);
  double loss_kd   = acc[1] / (double)BB;
  double wgt = ((double)(*epoch)) * 0.01 * 16.0;
  out[0] = (float)(loss_rank + wgt * loss_kd);
  out[1] = (float)loss_rank;
  out[2] = (float)loss_kd;
}

extern "C" void kernel_launch(void* const* d_in, const int* in_sizes, int n_in,
                              void* d_out, int out_size, void* d_ws, size_t ws_size,
                              hipStream_t stream)
{
  (void)in_sizes; (void)n_in; (void)out_size; (void)ws_size;
  const float* batch   = (const float*)d_in[0];
  const float* teacher = (const float*)d_in[1];
  const int*   labels  = (const int*)d_in[2];
  const int*   epoch   = (const int*)d_in[3];
  float* out  = (float*)d_out;
  double* acc = (double*)d_ws;
  int* nv     = (int*)((char*)d_ws + 16);

  hipMemsetAsync(d_ws, 0, 32, stream);
  crit_main<<<dim3(BB / R), dim3(T), 0, stream>>>(batch, teacher, labels, acc, nv);
  crit_final<<<dim3(1), dim3(1), 0, stream>>>(acc, nv, epoch, out);
}